// Round 8
// baseline (76.876 us; speedup 1.0000x reference)
//
#include <hip/hip_runtime.h>
#include <math.h>

constexpr int BDIM   = 1024;
constexpr int INDIM  = 512;
constexpr int OUTDIM = 512;

constexpr int NG  = 4;              // k-slices = waves per block
constexpr int KCH = INDIM / NG;     // 128 k per slice
constexpr int BK  = 16;             // k per staged chunk
constexpr int BT  = 16;             // batch rows per block
constexpr int TO  = 32;             // outputs per block

constexpr int XROW  = 72;           // floats per k-row of staging (72 mod 32 = 8 -> clean writes)
constexpr int XWAVE = BK * XROW;    // 1152 floats per wave-private x region
constexpr int PART_FLOATS = NG * 3 * BT * TO;  // 6144 floats = 24 KiB (> NG*XWAVE = 4608)

// prep: pack per-(k,o) weight quad {W1[k,o], W2[k,o], |W2[o,k]|, 0}
__global__ void prep_k(const float* __restrict__ wh1, const float* __restrict__ mh1,
                       const float* __restrict__ wh2, const float* __restrict__ mh2,
                       float4* __restrict__ wq) {
    int e = blockIdx.x * 256 + threadIdx.x;
    if (e >= INDIM * OUTDIM) return;
    int k = e >> 9, o = e & 511;
    int et = o * INDIM + k;
    float w1 = tanhf(wh1[e])  * (1.0f / (1.0f + expf(-mh1[e])));
    float w2 = tanhf(wh2[e])  * (1.0f / (1.0f + expf(-mh2[e])));
    float sw = fabsf(tanhf(wh2[et]) * (1.0f / (1.0f + expf(-mh2[et]))));
    wq[e] = float4{w1, w2, sw, 0.0f};
}

__global__ __launch_bounds__(256, 4) void main_k(
    const float* __restrict__ X, const float4* __restrict__ wq,
    const float* __restrict__ G1, float* __restrict__ out)
{
    __shared__ __align__(16) float smem[PART_FLOATS];

    const int t     = threadIdx.x;
    const int w     = t >> 6;          // k-slice 0..3 (one wave each)
    const int lane  = t & 63;
    const int o_sub = lane & 7;        // 8 output groups (x4 outputs each)
    const int r_sub = lane >> 3;       // 8 row groups (x2 rows each)
    const int o0    = blockIdx.x * TO;
    const int b0    = blockIdx.y * BT;

    float* xw = smem + w * XWAVE;      // wave-private x staging

    float accA[2][4] = {};
    float accL[2][4] = {};
    float accP[2][4];
    #pragma unroll
    for (int ri = 0; ri < 2; ++ri)
        #pragma unroll
        for (int oi = 0; oi < 4; ++oi) accP[ri][oi] = 1.0f;

    // stager mapping (within wave): 16 rows x 16 k; lane -> row=lane>>2, 4 k at (lane&3)*4
    const int srow = lane >> 2;
    const int k4   = (lane & 3) * 4;
    const int kbase = w * KCH;

    // prefetch first chunk's X
    float4 gx = *reinterpret_cast<const float4*>(&X[(b0 + srow) * INDIM + kbase + k4]);

    for (int c0 = 0; c0 < KCH; c0 += BK) {
        const int kg = kbase + c0;
        // derive + stage x quads {x, log2|x|, s, 0}
        {
            const float xa[4] = {gx.x, gx.y, gx.z, gx.w};
            #pragma unroll
            for (int j = 0; j < 4; ++j) {
                const float x = xa[j];
                const float l = log2f(fmaxf(fabsf(x), 1e-7f));
                const float s = (x > 0.f) ? 0.f : ((x < 0.f) ? -2.f : -1.f);
                *reinterpret_cast<float4*>(&xw[(k4 + j) * XROW + srow * 4]) = float4{x, l, s, 0.f};
            }
        }
        // prefetch next chunk's X
        if (c0 + BK < KCH) {
            gx = *reinterpret_cast<const float4*>(&X[(b0 + srow) * INDIM + kg + BK + k4]);
        }
        __syncthreads();   // staging visible to whole wave-front before reads

        // weight pipeline prologue: load kk=0 quads
        float4 wc[4];
        {
            const float4* wrow = wq + kg * OUTDIM + o0;
            #pragma unroll
            for (int oi = 0; oi < 4; ++oi) wc[oi] = wrow[o_sub + 8 * oi];
        }

        #pragma unroll 4
        for (int kk = 0; kk < BK; ++kk) {
            // issue next-kk weight loads (1-deep software pipeline)
            const int knext = (kg + kk + 1 < INDIM) ? (kg + kk + 1) : (INDIM - 1);
            const float4* wrowN = wq + knext * OUTDIM + o0;
            float4 wn[4];
            #pragma unroll
            for (int oi = 0; oi < 4; ++oi) wn[oi] = wrowN[o_sub + 8 * oi];
            // x quads from LDS (broadcast across 8 lanes, 2-way banks)
            float4 xq[2];
            #pragma unroll
            for (int ri = 0; ri < 2; ++ri)
                xq[ri] = *reinterpret_cast<const float4*>(&xw[kk * XROW + (r_sub * 2 + ri) * 4]);
            #pragma unroll
            for (int ri = 0; ri < 2; ++ri) {
                #pragma unroll
                for (int oi = 0; oi < 4; ++oi) {
                    accA[ri][oi] = fmaf(xq[ri].x, wc[oi].x, accA[ri][oi]);
                    accL[ri][oi] = fmaf(xq[ri].y, wc[oi].y, accL[ri][oi]);
                    accP[ri][oi] *= fmaf(xq[ri].z, wc[oi].z, 1.0f);
                }
            }
            #pragma unroll
            for (int oi = 0; oi < 4; ++oi) wc[oi] = wn[oi];
        }
        __syncthreads();   // reads done before next chunk's staging writes
    }

    // ---- dump per-wave partials (staging region aliased; all compute done)
    {
        #pragma unroll
        for (int ri = 0; ri < 2; ++ri) {
            const int row = r_sub * 2 + ri;
            #pragma unroll
            for (int oi = 0; oi < 4; ++oi) {
                const int o = o_sub + 8 * oi;
                smem[((w * 3 + 0) * BT + row) * TO + o] = accA[ri][oi];
                smem[((w * 3 + 1) * BT + row) * TO + o] = accL[ri][oi];
                smem[((w * 3 + 2) * BT + row) * TO + o] = accP[ri][oi];
            }
        }
    }
    __syncthreads();

    // combine 4 slices + epilogue: 256 threads x 2 outputs
    {
        const int idx2 = t * 2;
        const int row = idx2 >> 5;     // 0..15
        const int oc  = idx2 & 31;     // even
        float A[2] = {0, 0}, L[2] = {0, 0}, P[2] = {1, 1};
        #pragma unroll
        for (int s = 0; s < NG; ++s) {
            const float2 a = *reinterpret_cast<const float2*>(&smem[((s * 3 + 0) * BT + row) * TO + oc]);
            const float2 l = *reinterpret_cast<const float2*>(&smem[((s * 3 + 1) * BT + row) * TO + oc]);
            const float2 p = *reinterpret_cast<const float2*>(&smem[((s * 3 + 2) * BT + row) * TO + oc]);
            A[0] += a.x; A[1] += a.y;
            L[0] += l.x; L[1] += l.y;
            P[0] *= p.x; P[1] *= p.y;
        }
        const float2 gv = *reinterpret_cast<const float2*>(&G1[o0 + oc]);
        const float garr[2] = {gv.x, gv.y};
        constexpr float CAP = 28.853900817779268f;   // 20 * log2(e)
        float2 r;
        float* rp = &r.x;
        #pragma unroll
        for (int j = 0; j < 2; ++j) {
            const float g = 1.0f / (1.0f + expf(-garr[j]));
            const float m = exp2f(fminf(L[j], CAP));
            const float s = fminf(fmaxf(P[j], -1.0f), 1.0f);
            rp[j] = g * A[j] + (1.0f - g) * m * s;
        }
        *reinterpret_cast<float2*>(&out[(b0 + row) * OUTDIM + o0 + oc]) = r;
    }
}

extern "C" void kernel_launch(void* const* d_in, const int* in_sizes, int n_in,
                              void* d_out, int out_size, void* d_ws, size_t ws_size,
                              hipStream_t stream) {
    const float* X   = (const float*)d_in[0];
    const float* wh1 = (const float*)d_in[1];
    const float* mh1 = (const float*)d_in[2];
    const float* wh2 = (const float*)d_in[3];
    const float* mh2 = (const float*)d_in[4];
    const float* G1  = (const float*)d_in[5];
    float* out = (float*)d_out;
    float4* wq = (float4*)d_ws;   // 512*512*16B = 4 MiB

    prep_k<<<dim3((INDIM * OUTDIM + 255) / 256), 256, 0, stream>>>(wh1, mh1, wh2, mh2, wq);
    main_k<<<dim3(OUTDIM / TO, BDIM / BT), 256, 0, stream>>>(X, wq, G1, out);
}

// Round 9
// 72.509 us; speedup vs baseline: 1.0602x; 1.0602x over previous
//
#include <hip/hip_runtime.h>
#include <math.h>

constexpr int BDIM   = 1024;
constexpr int INDIM  = 512;
constexpr int OUTDIM = 512;

constexpr int TB = 16;            // batch rows per block
constexpr int TO = 32;            // outputs per block
constexpr int NW = 4;             // waves per block = k-slices
constexpr int KCH = INDIM / NW;   // 128 k per wave
constexpr int BK = 16;            // staged k per chunk

constexpr int XL_F = BK * TB * 2; // 512 floats: {x, log2|x|} per (kk,row)
constexpr int S_F  = BK * TB;     // 256 floats: sign-term per (kk,row)
constexpr int WREG = XL_F + S_F;  // 768 floats per wave-private region
constexpr int PART_F = NW * 3 * TB * TO;  // 6144 floats = 24 KiB (> NW*WREG = 3072)

#define F4(v, i) (&(v).x)[i]

__global__ void prep_k(const float* __restrict__ wh1, const float* __restrict__ mh1,
                       const float* __restrict__ wh2, const float* __restrict__ mh2,
                       float* __restrict__ W1p, float* __restrict__ W2p,
                       float* __restrict__ SWp) {
    int e = blockIdx.x * 256 + threadIdx.x;
    if (e >= INDIM * OUTDIM) return;
    int k = e >> 9, o = e & 511;
    int et = o * INDIM + k;
    W1p[e] = tanhf(wh1[e]) * (1.0f / (1.0f + expf(-mh1[e])));
    W2p[e] = tanhf(wh2[e]) * (1.0f / (1.0f + expf(-mh2[e])));
    SWp[e] = fabsf(tanhf(wh2[et]) * (1.0f / (1.0f + expf(-mh2[et]))));
}

__global__ __launch_bounds__(256, 4) void main_k(
    const float* __restrict__ X, const float* __restrict__ W1p,
    const float* __restrict__ W2p, const float* __restrict__ SWp,
    const float* __restrict__ G1, float* __restrict__ out)
{
    __shared__ __align__(16) float smem[PART_F];

    const int t     = threadIdx.x;
    const int w     = t >> 6;         // wave = k-slice 0..3
    const int lane  = t & 63;
    const int o_sub = lane & 7;       // 8 groups x 4 contiguous outputs
    const int r_sub = lane >> 3;      // 8 groups x 2 rows
    const int o0    = blockIdx.x * TO;
    const int b0    = blockIdx.y * TB;
    const int kbase = w * KCH;

    float* xl = smem + w * WREG;      // [BK][TB] float2 {x, l}
    float* sl = xl + XL_F;            // [BK][TB] float s

    // stager map: lane -> (row, 4 consecutive k)
    const int srow = lane >> 2;
    const int kq   = (lane & 3) * 4;

    float accA[2][4] = {};
    float accL[2][4] = {};
    float accP[2][4];
    #pragma unroll
    for (int ri = 0; ri < 2; ++ri)
        #pragma unroll
        for (int oi = 0; oi < 4; ++oi) accP[ri][oi] = 1.0f;

    // per-thread weight bases (4 contiguous outputs)
    const float* w1b = W1p + o0 + o_sub * 4;
    const float* w2b = W2p + o0 + o_sub * 4;
    const float* swb = SWp + o0 + o_sub * 4;

    // weight ring: slot kk&1, pipelined 2 ahead, continuous across chunks
    float4 w1r[2], w2r[2], swr[2];
    w1r[0] = *reinterpret_cast<const float4*>(w1b + (kbase + 0) * OUTDIM);
    w2r[0] = *reinterpret_cast<const float4*>(w2b + (kbase + 0) * OUTDIM);
    swr[0] = *reinterpret_cast<const float4*>(swb + (kbase + 0) * OUTDIM);
    w1r[1] = *reinterpret_cast<const float4*>(w1b + (kbase + 1) * OUTDIM);
    w2r[1] = *reinterpret_cast<const float4*>(w2b + (kbase + 1) * OUTDIM);
    swr[1] = *reinterpret_cast<const float4*>(swb + (kbase + 1) * OUTDIM);

    // X prefetch for chunk 0
    float4 gx = *reinterpret_cast<const float4*>(&X[(b0 + srow) * INDIM + kbase + kq]);

    for (int c0 = 0; c0 < KCH; c0 += BK) {
        // ---- stage this wave's x-tile (wave-private; no barrier needed)
        {
            const float xa[4] = {gx.x, gx.y, gx.z, gx.w};
            #pragma unroll
            for (int j = 0; j < 4; ++j) {
                const float x = xa[j];
                const float l = log2f(fmaxf(fabsf(x), 1e-7f));
                const float s = (x > 0.f) ? 0.f : ((x < 0.f) ? -2.f : -1.f);
                *reinterpret_cast<float2*>(&xl[(kq + j) * (TB * 2) + srow * 2]) = float2{x, l};
                sl[(kq + j) * TB + srow] = s;
            }
        }
        // prefetch next chunk's X
        if (c0 + BK < KCH)
            gx = *reinterpret_cast<const float4*>(&X[(b0 + srow) * INDIM + kbase + c0 + BK + kq]);

        // x ring prologue (reads queue behind this wave's writes in-order)
        float4 xq[2];
        float2 sq[2];
        xq[0] = *reinterpret_cast<const float4*>(&xl[0 * (TB * 2) + r_sub * 4]);
        sq[0] = *reinterpret_cast<const float2*>(&sl[0 * TB + r_sub * 2]);

        #pragma unroll
        for (int kk = 0; kk < BK; ++kk) {
            const int s = kk & 1;
            // issue next x operands early (different slot -> no WAR)
            if (kk < BK - 1) {
                xq[(kk + 1) & 1] = *reinterpret_cast<const float4*>(&xl[(kk + 1) * (TB * 2) + r_sub * 4]);
                sq[(kk + 1) & 1] = *reinterpret_cast<const float2*>(&sl[(kk + 1) * TB + r_sub * 2]);
            }
            // consume slot s
            #pragma unroll
            for (int ri = 0; ri < 2; ++ri) {
                const float xv = F4(xq[s], ri * 2);
                const float lv = F4(xq[s], ri * 2 + 1);
                const float sv = (ri == 0) ? sq[s].x : sq[s].y;
                #pragma unroll
                for (int oi = 0; oi < 4; ++oi) {
                    accA[ri][oi] = fmaf(xv, F4(w1r[s], oi), accA[ri][oi]);
                    accL[ri][oi] = fmaf(lv, F4(w2r[s], oi), accL[ri][oi]);
                    accP[ri][oi] *= fmaf(sv, F4(swr[s], oi), 1.0f);
                }
            }
            // reload slot s with k+2 (after consumption; clamped at tail)
            int k2 = kbase + c0 + kk + 2;
            k2 = (k2 < INDIM) ? k2 : (INDIM - 1);
            w1r[s] = *reinterpret_cast<const float4*>(w1b + k2 * OUTDIM);
            w2r[s] = *reinterpret_cast<const float4*>(w2b + k2 * OUTDIM);
            swr[s] = *reinterpret_cast<const float4*>(swb + k2 * OUTDIM);
        }
    }

    __syncthreads();   // all waves done with private staging; smem reused for partials

    // ---- dump per-wave partials
    #pragma unroll
    for (int ri = 0; ri < 2; ++ri) {
        const int row = r_sub * 2 + ri;
        #pragma unroll
        for (int oi = 0; oi < 4; ++oi) {
            const int o = o_sub * 4 + oi;
            smem[((w * 3 + 0) * TB + row) * TO + o] = accA[ri][oi];
            smem[((w * 3 + 1) * TB + row) * TO + o] = accL[ri][oi];
            smem[((w * 3 + 2) * TB + row) * TO + o] = accP[ri][oi];
        }
    }
    __syncthreads();

    // ---- combine 4 slices + epilogue: 256 threads x 2 outputs
    {
        const int idx2 = t * 2;
        const int row = idx2 >> 5;     // 0..15
        const int oc  = idx2 & 31;     // even
        float A[2] = {0, 0}, L[2] = {0, 0}, P[2] = {1, 1};
        #pragma unroll
        for (int gg = 0; gg < NW; ++gg) {
            const float2 a = *reinterpret_cast<const float2*>(&smem[((gg * 3 + 0) * TB + row) * TO + oc]);
            const float2 l = *reinterpret_cast<const float2*>(&smem[((gg * 3 + 1) * TB + row) * TO + oc]);
            const float2 p = *reinterpret_cast<const float2*>(&smem[((gg * 3 + 2) * TB + row) * TO + oc]);
            A[0] += a.x; A[1] += a.y;
            L[0] += l.x; L[1] += l.y;
            P[0] *= p.x; P[1] *= p.y;
        }
        const float2 gv = *reinterpret_cast<const float2*>(&G1[o0 + oc]);
        const float garr[2] = {gv.x, gv.y};
        constexpr float CAP = 28.853900817779268f;   // 20 * log2(e)
        float2 r;
        #pragma unroll
        for (int j = 0; j < 2; ++j) {
            const float g = 1.0f / (1.0f + expf(-garr[j]));
            const float m = exp2f(fminf(L[j], CAP));
            const float sg = fminf(fmaxf(P[j], -1.0f), 1.0f);
            (&r.x)[j] = g * A[j] + (1.0f - g) * m * sg;
        }
        *reinterpret_cast<float2*>(&out[(b0 + row) * OUTDIM + o0 + oc]) = r;
    }
}

extern "C" void kernel_launch(void* const* d_in, const int* in_sizes, int n_in,
                              void* d_out, int out_size, void* d_ws, size_t ws_size,
                              hipStream_t stream) {
    const float* X   = (const float*)d_in[0];
    const float* wh1 = (const float*)d_in[1];
    const float* mh1 = (const float*)d_in[2];
    const float* wh2 = (const float*)d_in[3];
    const float* mh2 = (const float*)d_in[4];
    const float* G1  = (const float*)d_in[5];
    float* out = (float*)d_out;
    float* W1p = (float*)d_ws;                      // 1 MiB each
    float* W2p = W1p + INDIM * OUTDIM;
    float* SWp = W2p + INDIM * OUTDIM;

    prep_k<<<dim3((INDIM * OUTDIM + 255) / 256), 256, 0, stream>>>(wh1, mh1, wh2, mh2, W1p, W2p, SWp);
    main_k<<<dim3(OUTDIM / TO, BDIM / TB), 256, 0, stream>>>(X, W1p, W2p, SWp, G1, out);
}

// Round 10
// 66.463 us; speedup vs baseline: 1.1567x; 1.0910x over previous
//
#include <hip/hip_runtime.h>
#include <math.h>

constexpr int B_   = 1024;
constexpr int IN_  = 512;
constexpr int OUT_ = 512;

constexpr int RB  = 32;           // rows per block
constexpr int CB  = 64;           // cols per block
constexpr int KW  = 128;          // k per wave (4 waves = full K)
constexpr int BK  = 8;            // k per staged chunk
constexpr int NCH = KW / BK;      // 16 chunks
constexpr int CHF = BK * 3 * 64;  // 1536 floats per weight chunk

// ws layout (floats): xT[512][1024], lT[512][1024], wP[8][512][3][64]
constexpr size_t XT_OFF = 0;
constexpr size_t LT_OFF = (size_t)IN_ * B_;
constexpr size_t WP_OFF = 2 * (size_t)IN_ * B_;

__device__ __forceinline__ float sigm(float z) { return 1.0f / (1.0f + expf(-z)); }

__global__ void prep_x(const float* __restrict__ X, float* __restrict__ xT,
                       float* __restrict__ lT) {
    int tid = blockIdx.x * 256 + threadIdx.x;      // 524288
    int b = tid & (B_ - 1);
    int k = tid >> 10;
    float x = X[b * IN_ + k];                      // strided read (L2-resident)
    xT[k * B_ + b] = x;                            // coalesced write
    lT[k * B_ + b] = log2f(fmaxf(fabsf(x), 1e-7f));
}

__global__ void prep_w(const float* __restrict__ wh1, const float* __restrict__ mh1,
                       const float* __restrict__ wh2, const float* __restrict__ mh2,
                       float* __restrict__ wP) {
    int tid = blockIdx.x * 256 + threadIdx.x;      // 262144
    int o = tid & 511, k = tid >> 9;
    float w1 = tanhf(wh1[k * OUT_ + o]) * sigm(mh1[k * OUT_ + o]);
    float w2 = tanhf(wh2[k * OUT_ + o]) * sigm(mh2[k * OUT_ + o]);
    float sw = fabsf(tanhf(wh2[o * IN_ + k]) * sigm(mh2[o * IN_ + k]));
    int ct = o >> 6, col = o & 63;
    size_t base = ((size_t)(ct * 512 + k) * 3) * 64 + col;
    wP[base + 0 * 64] = w1;
    wP[base + 1 * 64] = w2;
    wP[base + 2 * 64] = sw;
}

__device__ __forceinline__ void gl_lds16(const float* g, float* l) {
    __builtin_amdgcn_global_load_lds(
        (const __attribute__((address_space(1))) void*)g,
        (__attribute__((address_space(3))) void*)l, 16, 0, 0);
}

__global__ __launch_bounds__(256, 1) void main_k(
    const float* __restrict__ xT, const float* __restrict__ lT,
    const float* __restrict__ wP, const float* __restrict__ G1,
    float* __restrict__ out)
{
    __shared__ __align__(16) float smem[24576];   // 96 KiB: staging 48K / partials 96K

    const int t    = threadIdx.x;
    const int w    = t >> 6;            // wave 0..3 = k-slice
    const int lane = t & 63;
    const int cl   = lane & 7;          // 8 col-lanes x 8 outputs
    const int rl   = lane >> 3;         // 8 row-lanes x 4 rows
    const int bx   = blockIdx.x;        // col tile 0..7
    const int by   = blockIdx.y;        // row tile 0..31
    const int rowb = by * RB + rl * 4;  // thread's 4 rows (contiguous)
    const int kb   = w * KW;

    float* wbuf = smem + w * (2 * CHF); // wave-private double buffer

    float accA[4][8] = {}, accL[4][8] = {}, accP[4][8];
    #pragma unroll
    for (int ri = 0; ri < 4; ++ri)
        #pragma unroll
        for (int oi = 0; oi < 8; ++oi) accP[ri][oi] = 1.0f;

    const float* wsrc = wP + (size_t)(bx * 512 + kb) * 192;  // 192 floats per k

    // stage chunk 0 (6 x 1024B)
    #pragma unroll
    for (int i = 0; i < 6; ++i)
        gl_lds16(wsrc + i * 256 + lane * 4, wbuf + i * 256);

    #pragma unroll 1
    for (int c = 0; c < NCH; ++c) {
        float* buf = wbuf + (c & 1) * CHF;
        if (c + 1 < NCH) {
            const float* gsrc = wsrc + (size_t)(c + 1) * CHF;
            float* ldst = wbuf + ((c + 1) & 1) * CHF;
            #pragma unroll
            for (int i = 0; i < 6; ++i)
                gl_lds16(gsrc + i * 256 + lane * 4, ldst + i * 256);
            asm volatile("s_waitcnt vmcnt(6)" ::: "memory");  // chunk c landed
        } else {
            asm volatile("s_waitcnt vmcnt(0)" ::: "memory");
        }
        const int k0 = kb + c * BK;

        #pragma unroll
        for (int kk = 0; kk < BK; ++kk) {
            // x-side: tiny broadcast VMEM reads (128B span per instr, L2-hot)
            const float4 xq = *reinterpret_cast<const float4*>(&xT[(k0 + kk) * B_ + rowb]);
            const float4 lq = *reinterpret_cast<const float4*>(&lT[(k0 + kk) * B_ + rowb]);
            // w-side: LDS, 6 b128, 2-way banks only
            const float* wrow = buf + kk * 192;
            const float4 w1a = *reinterpret_cast<const float4*>(&wrow[0 * 64 + cl * 8]);
            const float4 w1b = *reinterpret_cast<const float4*>(&wrow[0 * 64 + cl * 8 + 4]);
            const float4 w2a = *reinterpret_cast<const float4*>(&wrow[1 * 64 + cl * 8]);
            const float4 w2b = *reinterpret_cast<const float4*>(&wrow[1 * 64 + cl * 8 + 4]);
            const float4 swa = *reinterpret_cast<const float4*>(&wrow[2 * 64 + cl * 8]);
            const float4 swb = *reinterpret_cast<const float4*>(&wrow[2 * 64 + cl * 8 + 4]);
            const float xs[4] = {xq.x, xq.y, xq.z, xq.w};
            const float ls[4] = {lq.x, lq.y, lq.z, lq.w};
            float ss[4];
            #pragma unroll
            for (int ri = 0; ri < 4; ++ri)
                ss[ri] = (xs[ri] < 0.f) ? -2.f : ((xs[ri] == 0.f) ? -1.f : 0.f);
            const float w1v[8] = {w1a.x, w1a.y, w1a.z, w1a.w, w1b.x, w1b.y, w1b.z, w1b.w};
            const float w2v[8] = {w2a.x, w2a.y, w2a.z, w2a.w, w2b.x, w2b.y, w2b.z, w2b.w};
            const float swv[8] = {swa.x, swa.y, swa.z, swa.w, swb.x, swb.y, swb.z, swb.w};
            #pragma unroll
            for (int ri = 0; ri < 4; ++ri) {
                #pragma unroll
                for (int oi = 0; oi < 8; ++oi) {
                    accA[ri][oi] = fmaf(xs[ri], w1v[oi], accA[ri][oi]);
                    accL[ri][oi] = fmaf(ls[ri], w2v[oi], accL[ri][oi]);
                    accP[ri][oi] *= fmaf(ss[ri], swv[oi], 1.0f);
                }
            }
        }
    }

    __syncthreads();  // staging dead; reuse full 96K for partials

    // dump partials: [w][plane][row32][col64]
    #pragma unroll
    for (int ri = 0; ri < 4; ++ri) {
        const int row = rl * 4 + ri;
        #pragma unroll
        for (int pl = 0; pl < 3; ++pl) {
            float* dst = smem + (((w * 3 + pl) * RB + row) * CB + cl * 8);
            const float* src = (pl == 0) ? accA[ri] : (pl == 1) ? accL[ri] : accP[ri];
            *reinterpret_cast<float4*>(dst)     = float4{src[0], src[1], src[2], src[3]};
            *reinterpret_cast<float4*>(dst + 4) = float4{src[4], src[5], src[6], src[7]};
        }
    }
    __syncthreads();

    // combine 4 k-slices + epilogue: 256 threads x 8 outputs
    {
        const int row = t >> 3;
        const int cq  = (t & 7) * 8;
        float A[8] = {}, L[8] = {}, P[8] = {1, 1, 1, 1, 1, 1, 1, 1};
        #pragma unroll
        for (int wg = 0; wg < 4; ++wg) {
            #pragma unroll
            for (int h = 0; h < 2; ++h) {
                const float4 a = *reinterpret_cast<const float4*>(
                    &smem[((wg * 3 + 0) * RB + row) * CB + cq + h * 4]);
                const float4 l = *reinterpret_cast<const float4*>(
                    &smem[((wg * 3 + 1) * RB + row) * CB + cq + h * 4]);
                const float4 p = *reinterpret_cast<const float4*>(
                    &smem[((wg * 3 + 2) * RB + row) * CB + cq + h * 4]);
                A[h*4+0] += a.x; A[h*4+1] += a.y; A[h*4+2] += a.z; A[h*4+3] += a.w;
                L[h*4+0] += l.x; L[h*4+1] += l.y; L[h*4+2] += l.z; L[h*4+3] += l.w;
                P[h*4+0] *= p.x; P[h*4+1] *= p.y; P[h*4+2] *= p.z; P[h*4+3] *= p.w;
            }
        }
        constexpr float CAP = 28.853900817779268f;   // 20 * log2(e)
        float res[8];
        #pragma unroll
        for (int j = 0; j < 8; ++j) {
            const float g = sigm(G1[bx * CB + cq + j]);
            const float m = exp2f(fminf(L[j], CAP));
            const float sg = fminf(fmaxf(P[j], -1.0f), 1.0f);
            res[j] = g * A[j] + (1.0f - g) * m * sg;
        }
        float* op = &out[(by * RB + row) * OUT_ + bx * CB + cq];
        *reinterpret_cast<float4*>(op)     = float4{res[0], res[1], res[2], res[3]};
        *reinterpret_cast<float4*>(op + 4) = float4{res[4], res[5], res[6], res[7]};
    }
}

extern "C" void kernel_launch(void* const* d_in, const int* in_sizes, int n_in,
                              void* d_out, int out_size, void* d_ws, size_t ws_size,
                              hipStream_t stream) {
    const float* X   = (const float*)d_in[0];
    const float* wh1 = (const float*)d_in[1];
    const float* mh1 = (const float*)d_in[2];
    const float* wh2 = (const float*)d_in[3];
    const float* mh2 = (const float*)d_in[4];
    const float* G1  = (const float*)d_in[5];
    float* out = (float*)d_out;
    float* ws  = (float*)d_ws;
    float* xT  = ws + XT_OFF;
    float* lT  = ws + LT_OFF;
    float* wPp = ws + WP_OFF;   // total ws use: 7 MiB

    prep_x<<<dim3((B_ * IN_) / 256), 256, 0, stream>>>(X, xT, lT);
    prep_w<<<dim3((IN_ * OUT_) / 256), 256, 0, stream>>>(wh1, mh1, wh2, mh2, wPp);
    main_k<<<dim3(OUT_ / CB, B_ / RB), 256, 0, stream>>>(xT, lT, wPp, G1, out);
}